// Round 6
// baseline (215.512 us; speedup 1.0000x reference)
//
#include <hip/hip_runtime.h>
#include <stdint.h>
#include <stddef.h>

typedef _Float16 f16;
typedef _Float16 half8 __attribute__((ext_vector_type(8)));
typedef _Float16 half4 __attribute__((ext_vector_type(4)));
typedef float floatx4 __attribute__((ext_vector_type(4)));

__device__ __forceinline__ floatx4 mfma16(half8 a, half8 b, floatx4 c) {
    return __builtin_amdgcn_mfma_f32_16x16x32_f16(a, b, c, 0, 0, 0);
}

typedef __attribute__((address_space(3))) void       lds_void_t;
typedef const __attribute__((address_space(1))) void gconst_void_t;

// async 16B/lane global->LDS; lds dest = wave-uniform base + lane*16
__device__ __forceinline__ void async_copy16(void* lds, const void* g) {
    __builtin_amdgcn_global_load_lds((gconst_void_t*)g, (lds_void_t*)lds, 16, 0, 0);
}

// ---------------- fused pre-pass ----------------
// blocks [0,2048): convert x f32->f16 row-major
// blocks [2048,2816): transpose w_attn [1024,3072] -> wattnT [3072,1024] f16
// blocks [2816,3072): transpose w_proj [1024,1024] -> wprojT [1024,1024] f16
__global__ __launch_bounds__(256)
void prepass(const float* __restrict__ x, const float* __restrict__ w_attn,
             const float* __restrict__ w_proj,
             f16* __restrict__ xh, f16* __restrict__ wattnT, f16* __restrict__ wprojT)
{
    __shared__ __align__(16) f16 t[64][72];
    const int bid = blockIdx.x;
    if (bid < 2048) {
        const size_t i = ((size_t)bid * 256 + threadIdx.x) * 8;
        floatx4 a = *(const floatx4*)(x + i);
        floatx4 b = *(const floatx4*)(x + i + 4);
        half8 h;
        h[0]=(f16)a[0]; h[1]=(f16)a[1]; h[2]=(f16)a[2]; h[3]=(f16)a[3];
        h[4]=(f16)b[0]; h[5]=(f16)b[1]; h[6]=(f16)b[2]; h[7]=(f16)b[3];
        *(half8*)(xh + i) = h;
        return;
    }
    const float* W; f16* WT; int Nsz, bx, by;
    if (bid < 2816) {
        W = w_attn; WT = wattnT; Nsz = 3072;
        const int r = bid - 2048; by = r / 48; bx = r - by * 48;
    } else {
        W = w_proj; WT = wprojT; Nsz = 1024;
        const int r = bid - 2816; by = r >> 4; bx = r & 15;
    }
    const int k0 = by << 6;
    const int n0 = bx << 6;
    {
        const int r  = threadIdx.x >> 2;
        const int c0 = (threadIdx.x & 3) << 4;
        #pragma unroll
        for (int i = 0; i < 4; ++i) {
            const int c = c0 + (i << 2);
            floatx4 v = *(const floatx4*)(W + (size_t)(k0 + r) * Nsz + n0 + c);
            t[c + 0][r] = (f16)v[0];
            t[c + 1][r] = (f16)v[1];
            t[c + 2][r] = (f16)v[2];
            t[c + 3][r] = (f16)v[3];
        }
    }
    __syncthreads();
    {
        const int n  = threadIdx.x >> 2;
        const int kc = (threadIdx.x & 3) << 4;
        #pragma unroll
        for (int i = 0; i < 2; ++i) {
            half8 h = *(half8*)&t[n][kc + (i << 3)];
            *(half8*)(WT + (size_t)(n0 + n) * 1024 + k0 + kc + (i << 3)) = h;
        }
    }
}

// ---------------- QKV GEMM ----------------
// C = xh[4096,1024] @ wattnT[3072,1024]^T + b_attn, written to per-head layouts:
//   Q: [bh][t][d]  K: [bh][t][d]  V: [bh][d][t] (transposed, packed half4 stores)
__global__ __launch_bounds__(256, 2)
void gemm_qkv(const f16* __restrict__ A, const f16* __restrict__ BT,
              const float* __restrict__ bias, f16* __restrict__ QKV)
{
    __shared__ __align__(16) f16 As[128 * 32];
    __shared__ __align__(16) f16 Bs[128 * 32];

    const int tid  = threadIdx.x;
    const int wave = tid >> 6;
    const int lane = tid & 63;
    const int quad = lane >> 4;
    const int l16  = lane & 15;
    const int wm   = (wave >> 1) * 64;
    const int wn   = (wave & 1) * 64;
    const int m0   = blockIdx.y * 128;
    const int n0   = blockIdx.x * 128;
    const int Ksz  = 1024;

    const int srow  = lane >> 2;
    const int skoff = (lane & 3) << 3;

    const f16* Ab = A  + (size_t)(m0 + wave * 16 + srow) * Ksz + skoff;
    const f16* Bb = BT + (size_t)(n0 + wave * 16 + srow) * Ksz + skoff;
    f16* AsW = &As[wave * 16 * 32];
    f16* BsW = &Bs[wave * 16 * 32];
    const size_t seg = (size_t)64 * Ksz;

    floatx4 acc[4][4] = {};

    for (int kc = 0; kc < Ksz; kc += 32) {
        async_copy16(AsW,           Ab + kc);
        async_copy16(AsW + 64 * 32, Ab + kc + seg);
        async_copy16(BsW,           Bb + kc);
        async_copy16(BsW + 64 * 32, Bb + kc + seg);
        asm volatile("s_waitcnt vmcnt(0)" ::: "memory");
        __syncthreads();

        half8 a[4], b[4];
        #pragma unroll
        for (int mt = 0; mt < 4; ++mt)
            a[mt] = *(const half8*)&As[(wm + mt * 16 + l16) * 32 + (quad << 3)];
        #pragma unroll
        for (int nt = 0; nt < 4; ++nt)
            b[nt] = *(const half8*)&Bs[(wn + nt * 16 + l16) * 32 + (quad << 3)];
        #pragma unroll
        for (int mt = 0; mt < 4; ++mt)
            #pragma unroll
            for (int nt = 0; nt < 4; ++nt)
                acc[mt][nt] = mfma16(a[mt], b[nt], acc[mt][nt]);
        __syncthreads();
    }

    const size_t HSZ = (size_t)32 * 2048 * 64;   // one of Q/K/V regions
    #pragma unroll
    for (int mt = 0; mt < 4; ++mt) {
        #pragma unroll
        for (int nt = 0; nt < 4; ++nt) {
            const int col  = n0 + wn + nt * 16 + l16;
            const float bv = bias[col];
            const int row0 = m0 + wm + mt * 16 + (quad << 2);
            const int bb   = row0 >> 11;
            const int t0   = row0 & 2047;
            const int hh   = (col >> 6) & 15;
            const int d    = col & 63;
            float v0 = acc[mt][nt][0] + bv;
            float v1 = acc[mt][nt][1] + bv;
            float v2 = acc[mt][nt][2] + bv;
            float v3 = acc[mt][nt][3] + bv;
            if (col < 2048) {   // Q or K: [bh][t][d]
                f16* dst = QKV + (size_t)(col >> 10) * HSZ
                         + (((size_t)(bb * 16 + hh) * 2048 + t0) << 6) + d;
                dst[0]   = (f16)v0;
                dst[64]  = (f16)v1;
                dst[128] = (f16)v2;
                dst[192] = (f16)v3;
            } else {            // V^T: [bh][d][t], 4 consecutive t -> half4
                half4 h; h[0]=(f16)v0; h[1]=(f16)v1; h[2]=(f16)v2; h[3]=(f16)v3;
                *(half4*)(QKV + 2 * HSZ
                          + (((size_t)(bb * 16 + hh) << 6) + d) * 2048 + t0) = h;
            }
        }
    }
}

// ---------------- proj GEMM: 128x64 tile (512 blocks = 2/CU) ----------------
__global__ __launch_bounds__(256, 2)
void gemm_proj(const f16* __restrict__ A, const f16* __restrict__ BT,
               const float* __restrict__ bias, float* __restrict__ C)
{
    __shared__ __align__(16) f16 As[128 * 32];
    __shared__ __align__(16) f16 Bs[64 * 32];

    const int tid  = threadIdx.x;
    const int wave = tid >> 6;
    const int lane = tid & 63;
    const int quad = lane >> 4;
    const int l16  = lane & 15;
    const int wm   = (wave >> 1) * 64;
    const int wn   = (wave & 1) * 32;
    const int m0   = blockIdx.y * 128;
    const int n0   = blockIdx.x * 64;
    const int Ksz  = 1024;

    const int srow  = lane >> 2;
    const int skoff = (lane & 3) << 3;

    const f16* Ab = A  + (size_t)(m0 + wave * 16 + srow) * Ksz + skoff;
    const f16* Bb = BT + (size_t)(n0 + wave * 16 + srow) * Ksz + skoff;
    f16* AsW = &As[wave * 16 * 32];
    f16* BsW = &Bs[wave * 16 * 32];
    const size_t seg = (size_t)64 * Ksz;

    floatx4 acc[4][2] = {};

    for (int kc = 0; kc < Ksz; kc += 32) {
        async_copy16(AsW,           Ab + kc);
        async_copy16(AsW + 64 * 32, Ab + kc + seg);
        async_copy16(BsW,           Bb + kc);
        asm volatile("s_waitcnt vmcnt(0)" ::: "memory");
        __syncthreads();

        half8 a[4], b[2];
        #pragma unroll
        for (int mt = 0; mt < 4; ++mt)
            a[mt] = *(const half8*)&As[(wm + mt * 16 + l16) * 32 + (quad << 3)];
        #pragma unroll
        for (int nt = 0; nt < 2; ++nt)
            b[nt] = *(const half8*)&Bs[(wn + nt * 16 + l16) * 32 + (quad << 3)];
        #pragma unroll
        for (int mt = 0; mt < 4; ++mt)
            #pragma unroll
            for (int nt = 0; nt < 2; ++nt)
                acc[mt][nt] = mfma16(a[mt], b[nt], acc[mt][nt]);
        __syncthreads();
    }

    #pragma unroll
    for (int mt = 0; mt < 4; ++mt) {
        #pragma unroll
        for (int nt = 0; nt < 2; ++nt) {
            const int col  = n0 + wn + nt * 16 + l16;
            const float bv = bias[col];
            #pragma unroll
            for (int r = 0; r < 4; ++r) {
                const int row = m0 + wm + mt * 16 + (quad << 2) + r;
                C[(size_t)row * 1024 + col] = acc[mt][nt][r] + bv;
            }
        }
    }
}

// ---------------- Flash attention, causal ----------------
// Grid (bh=32, j=32) = 1024 blocks, 4 waves each; wave owns 16 q rows of
// q-block j (j = 31-blockIdx.y so heavy blocks dispatch first).
// XCD affinity: linear block id = bh + 32*y -> XCD = bh%8, so all q-blocks of
// one (b,h) share an XCD; 4 bh/XCD * 512KB K+V = 2MB fits the 4MB L2.
// S^T = K*Q^T; V via global_load_lds DMA from V^T (XOR swizzle, conflict-free);
// fixed-max softmax; K reg dbuf; V LDS dbuf.
__global__ __launch_bounds__(256, 2)
void attn_fwd(const f16* __restrict__ Qb, const f16* __restrict__ Kb,
              const f16* __restrict__ Vb, f16* __restrict__ attn_out)
{
    const int bh   = blockIdx.x;
    const int j    = 31 - blockIdx.y;
    const int head = bh & 15;
    const int b    = bh >> 4;
    const int tid  = threadIdx.x;
    const int wave = tid >> 6;
    const int lane = tid & 63;
    const int quad = lane >> 4;
    const int l16  = lane & 15;

    __shared__ __align__(16) f16 Vt[2][64 * 64];   // [buf][d][kv], kv chunk8 ^ (d&7)
    __shared__ __align__(16) f16 Ps[4][16 * 64];   // per-wave P[q][kv], same swizzle

    const f16* Qh = Qb + ((size_t)bh << 17);
    const f16* Kh = Kb + ((size_t)bh << 17);
    const f16* Vh = Vb + ((size_t)bh << 17);

    // V DMA: wave stages d rows 16w..16w+15; instr g covers rows +8g..+8g+7.
    // lane L -> d-row r8=L>>3, source kv-chunk c8=(L&7)^r8 (XOR-swizzled LDS).
    const int r8 = lane >> 3;
    const int c8 = (lane & 7) ^ r8;
    const f16* vsrcA = Vh + (size_t)(wave * 16 + r8) * 2048 + c8 * 8;
    const f16* vsrcB = vsrcA + (size_t)8 * 2048;

    half8 kf[8], kn[8];
    half8 qf0, qf1;
    floatx4 o[4];
    float lp;

    auto loadK = [&](int kv0, half8* dst) {
        const f16* kp = Kh + (size_t)(kv0 + l16) * 64 + (quad << 3);
        #pragma unroll
        for (int t = 0; t < 4; ++t) {
            dst[2 * t]     = *(const half8*)(kp + t * 16 * 64);
            dst[2 * t + 1] = *(const half8*)(kp + t * 16 * 64 + 32);
        }
    };
    auto dmaV = [&](int kv0, int buf) {
        async_copy16(&Vt[buf][(wave * 16) * 64],     vsrcA + kv0);
        async_copy16(&Vt[buf][(wave * 16 + 8) * 64], vsrcB + kv0);
    };

    const int sw = l16 & 7;   // swizzle key (= d&7 and q&7 for our rows)
    const int n  = j + 1;

    auto body = [&](int kc, half8* kcur, half8* knxt) {
        __syncthreads();      // prev-iter DMA drained (vmcnt0 pre-barrier)
        if (kc + 1 < n) {
            loadK((kc + 1) << 6, knxt);
            dmaV((kc + 1) << 6, (kc + 1) & 1);
        }
        // S^T = K * Q^T : C-layout col=l16=q, row=quad*4+r=kv (within 16-tile)
        floatx4 s[4] = {};
        #pragma unroll
        for (int t = 0; t < 4; ++t) {
            s[t] = mfma16(kcur[2 * t],     qf0, s[t]);
            s[t] = mfma16(kcur[2 * t + 1], qf1, s[t]);
        }
        const bool diag = (kc == j);
        const int qrel = (wave << 4) + l16;
        #pragma unroll
        for (int t = 0; t < 4; ++t) {
            float p0 = __builtin_amdgcn_exp2f(s[t][0]);
            float p1 = __builtin_amdgcn_exp2f(s[t][1]);
            float p2 = __builtin_amdgcn_exp2f(s[t][2]);
            float p3 = __builtin_amdgcn_exp2f(s[t][3]);
            if (diag) {
                const int kvb = t * 16 + (quad << 2);
                p0 = (kvb     <= qrel) ? p0 : 0.f;
                p1 = (kvb + 1 <= qrel) ? p1 : 0.f;
                p2 = (kvb + 2 <= qrel) ? p2 : 0.f;
                p3 = (kvb + 3 <= qrel) ? p3 : 0.f;
            }
            lp += (p0 + p1) + (p2 + p3);
            half4 pk; pk[0]=(f16)p0; pk[1]=(f16)p1; pk[2]=(f16)p2; pk[3]=(f16)p3;
            const int c = t * 2 + (quad >> 1);
            *(half4*)&Ps[wave][(l16 << 6) + ((c ^ sw) << 3) + ((quad & 1) << 2)] = pk;
        }
        asm volatile("s_waitcnt lgkmcnt(0)" ::: "memory");
        half8 pf0 = *(const half8*)&Ps[wave][(l16 << 6) + (((quad    ) ^ sw) << 3)];
        half8 pf1 = *(const half8*)&Ps[wave][(l16 << 6) + (((quad + 4) ^ sw) << 3)];
        const f16* vbuf = &Vt[kc & 1][0];
        #pragma unroll
        for (int dt = 0; dt < 4; ++dt) {
            const f16* vrow = vbuf + ((dt * 16 + l16) << 6);
            half8 vf0 = *(const half8*)(vrow + (((quad    ) ^ sw) << 3));
            half8 vf1 = *(const half8*)(vrow + (((quad + 4) ^ sw) << 3));
            o[dt] = mfma16(pf0, vf0, o[dt]);
            o[dt] = mfma16(pf1, vf1, o[dt]);
        }
    };

    const int qrow0 = j * 64 + wave * 16;
    {
        const f16* qp = Qh + (size_t)(qrow0 + l16) * 64 + (quad << 3);
        qf0 = *(const half8*)qp;
        qf1 = *(const half8*)(qp + 32);
    }
    const f16 qs = (f16)0.1803368801f;   // (1/8) * log2(e)
    #pragma unroll
    for (int i = 0; i < 8; ++i) { qf0[i] *= qs; qf1[i] *= qs; }
    o[0] = o[1] = o[2] = o[3] = (floatx4){0.f, 0.f, 0.f, 0.f};
    lp = 0.f;

    loadK(0, kf);
    dmaV(0, 0);
    int kc = 0;
    while (kc + 2 <= n) { body(kc, kf, kn); body(kc + 1, kn, kf); kc += 2; }
    if (kc < n) body(kc, kf, kn);   // kc even here -> chunk in kf

    // epilogue: reduce l over quads, transpose inv via shuffles, write O
    float l = lp;
    l += __shfl_xor(l, 16);
    l += __shfl_xor(l, 32);
    const float inv = 1.f / l;
    #pragma unroll
    for (int r = 0; r < 4; ++r) {
        const float invr = __shfl(inv, (quad << 2) + r);
        const int row = (b << 11) + qrow0 + (quad << 2) + r;
        f16* op = attn_out + (size_t)row * 1024 + head * 64 + l16;
        #pragma unroll
        for (int dt = 0; dt < 4; ++dt)
            op[dt * 16] = (f16)(o[dt][r] * invr);
    }
}

extern "C" void kernel_launch(void* const* d_in, const int* in_sizes, int n_in,
                              void* d_out, int out_size, void* d_ws, size_t ws_size,
                              hipStream_t stream)
{
    const float* x      = (const float*)d_in[0];
    const float* w_attn = (const float*)d_in[1];
    const float* b_attn = (const float*)d_in[2];
    const float* w_proj = (const float*)d_in[3];
    const float* b_proj = (const float*)d_in[4];
    float* y = (float*)d_out;

    f16* xh       = (f16*)d_ws;                         // [4096,1024]
    f16* wattnT   = xh + (size_t)4096 * 1024;           // [3072,1024]
    f16* wprojT   = wattnT + (size_t)3072 * 1024;       // [1024,1024]
    f16* qkv      = wprojT + (size_t)1024 * 1024;       // Q,K: [32][2048][64]; V: [32][64][2048]
    f16* attn_out = qkv + (size_t)3 * 32 * 2048 * 64;   // [4096,1024]

    const size_t HSZ = (size_t)32 * 2048 * 64;

    prepass<<<dim3(3072), dim3(256), 0, stream>>>(x, w_attn, w_proj, xh, wattnT, wprojT);
    gemm_qkv<<<dim3(24, 32), dim3(256), 0, stream>>>(xh, wattnT, b_attn, qkv);
    attn_fwd<<<dim3(32, 32), dim3(256), 0, stream>>>(qkv, qkv + HSZ, qkv + 2 * HSZ, attn_out);
    gemm_proj<<<dim3(16, 32), dim3(256), 0, stream>>>(attn_out, wprojT, b_proj, y);
}